// Round 14
// baseline (1364.428 us; speedup 1.0000x reference)
//
#include <hip/hip_runtime.h>
#include <math.h>

typedef __attribute__((ext_vector_type(8))) short s16x8;
typedef __attribute__((ext_vector_type(4))) float f32x4;
typedef unsigned long long ull;

constexpr float LOG2E = 1.4426950408889634f;

__device__ __forceinline__ unsigned short f2bf(float f) {
  unsigned int x = __builtin_bit_cast(unsigned int, f);
  x += 0x7fffu + ((x >> 16) & 1u);          // RNE
  return (unsigned short)(x >> 16);
}
__device__ __forceinline__ float fexp2(float x) { return __builtin_amdgcn_exp2f(x); }
__device__ __forceinline__ float frcp(float x)  { return __builtin_amdgcn_rcpf(x); }

#define MFMA16(A, B, Cc) __builtin_amdgcn_mfma_f32_16x16x32_bf16((A), (B), (Cc), 0, 0, 0)

constexpr int TT = 512;
constexpr int NB = 1024;

struct U128 { ull lo, hi; };

// Shared-denominator LSTM cell (round-9 validated, absmax 0.0127 identical).
// Inputs pre-scaled: i,f,o by -log2e; g by +2log2e.
__device__ __forceinline__ float lstm_cell(float ai, float af, float ag, float ao,
                                           float& c) {
  const float F = fexp2(fminf(af, 29.f));
  const float I = fexp2(fminf(ai, 29.f));
  const float G = fexp2(fminf(ag, 29.f));
  const float O = fexp2(fminf(ao, 29.f));
  const float P   = (1.f + I) * (1.f + G);
  const float num = c * P + (G - 1.f) * (1.f + F);
  const float cn  = num * frcp((1.f + F) * P);
  c = cn;
  const float E = fexp2(fminf(cn * (2.f * LOG2E), 60.f));
  return (E - 1.f) * frcp((1.f + O) * (E + 1.f));
}

// ---------------------------------------------------------------------------
// LDS-MINIMAL scan: 16 rows/block, 8 waves. LDS holds ONLY the h double
// buffer (8 KiB). Per step/CU: 32 ds_read_b128 + 8 ds_write_b64 (~430 cyc)
// vs round-6's ~96+16 (~1500 cyc incl conflicts) -- the ablation-isolated
// bottleneck (lstmB=C=D~430us floor = LDS+MFMA core).
//   * bias -> 4 f32x4 registers (was 32 b128 LDS reads/CU/step)
//   * x fragments: per-lane GLOBAL loads (16B contiguous each), issued one
//     full step ahead (latency hides under step t's MFMA/trans); data is
//     MALL-resident (producer just wrote it). No x_s, no staging writes.
//   * frag regs ping-pong via 2-step unrolled loop (static indexing).
// Sync: ONE __syncthreads per step (h dbuf parity covers RAW+WAR; its
// vmcnt(0) drains ys stores -> flag F=t publishable at top of step t).
// Flags: F => ys[0,F) visible at MALL. Consumer loads frag(t+1) at top of
// step t gated by avail >= t+2 (steady-state lag ~2-3 steps; producers
// never wait on consumers -> deadlock-free).
// ---------------------------------------------------------------------------
template <int DIN, bool FIRST, bool LAST>
__device__ __forceinline__ void scan_layer(
    unsigned short* h_s,                      // [2][16][128] swizzled dbuf
    const float* __restrict__ xin,            // FIRST: x [B][T][32] f32
    unsigned short* ys,                       // [T][B][128] bf16 pipe (in-place)
    const float* __restrict__ Wih, const float* __restrict__ Whh,
    const float* __restrict__ bias, float* __restrict__ hT,
    int* prog_in, int* prog_out, int bblk)
{
  constexpr int KTX = DIN / 32;               // 1 or 4 x k-tiles
  const int tid = threadIdx.x;
  const int wv = tid >> 6, ln = tid & 63, l15 = ln & 15, lg = ln >> 4;
  const int row0 = bblk * 16;
  const int hcol = wv * 16 + lg * 4;
  const int swzh = (l15 & 7) << 3;

  // ---- weights -> regs (bf16, pre-scaled by -log2e / 2log2e) ----
  s16x8 bfx[4][KTX], bfh[4][4];
#pragma unroll
  for (int j = 0; j < 4; ++j) {
    const float scl = (j == 2) ? (2.0f * LOG2E) : (-LOG2E);
    const int n = j * 128 + wv * 16 + l15;
#pragma unroll
    for (int kt = 0; kt < KTX; ++kt) {
      s16x8 f;
#pragma unroll
      for (int e = 0; e < 8; ++e) f[e] = (short)f2bf(Wih[n * DIN + kt * 32 + lg * 8 + e] * scl);
      bfx[j][kt] = f;
    }
#pragma unroll
    for (int kt = 0; kt < 4; ++kt) {
      s16x8 f;
#pragma unroll
      for (int e = 0; e < 8; ++e) f[e] = (short)f2bf(Whh[n * 128 + kt * 32 + lg * 8 + e] * scl);
      bfh[j][kt] = f;
    }
  }
  // ---- bias -> registers (pre-scaled); D rows = j*128 + hcol + r ----
  f32x4 bj[4];
#pragma unroll
  for (int j = 0; j < 4; ++j) {
    const float scl = (j == 2) ? (2.0f * LOG2E) : (-LOG2E);
    f32x4 b;
#pragma unroll
    for (int r = 0; r < 4; ++r) b[r] = bias[j * 128 + hcol + r] * scl;
    bj[j] = b;
  }
  for (int i = tid; i < 2 * 16 * 128; i += 512) h_s[i] = 0;   // h0 = 0

  // ---- fragment register buffers (ping-pong A/B) ----
  ull   frA[2 * KTX], frB[2 * KTX];           // !FIRST: kt -> {lo,hi} 16B
  f32x4 fxA[2],       fxB[2];                 // FIRST: 8 f32 per step

  // ---- prologue: acquire + load frag(0) -> A ----
  int avail = 0;
  if (FIRST) {
    const float* p = xin + (size_t)(row0 + l15) * (TT * 32) + lg * 8;
    fxA[0] = *reinterpret_cast<const f32x4*>(p);
    fxA[1] = *reinterpret_cast<const f32x4*>(p + 4);
  } else {
    int f;
    do { f = __hip_atomic_load(prog_in, __ATOMIC_RELAXED, __HIP_MEMORY_SCOPE_AGENT); } while (f < 2);
    avail = f;
#pragma unroll
    for (int kt = 0; kt < KTX; ++kt) {
      const ull* base = (ull*)ys + ((size_t)(row0 + l15) * 128 + kt * 32 + lg * 8) / 4;
      frA[2 * kt]     = __hip_atomic_load(base,     __ATOMIC_RELAXED, __HIP_MEMORY_SCOPE_AGENT);
      frA[2 * kt + 1] = __hip_atomic_load(base + 1, __ATOMIC_RELAXED, __HIP_MEMORY_SCOPE_AGENT);
    }
  }
  __syncthreads();                            // h0 visible

  float cst[4] = {0.f, 0.f, 0.f, 0.f};

  auto step = [&](int t, ull* cu, ull* nx, f32x4* fc, f32x4* fn) {
    // ---- publish lagged flag (steps < t drained by prev step's sync) ----
    if (!LAST && tid == 0 && t > 0)
      __hip_atomic_store(prog_out, t, __ATOMIC_RELAXED, __HIP_MEMORY_SCOPE_AGENT);

    // ---- ensure pipe depth, then load frag(t+1) -> next regs ----
    int f_new = 0;
    if (!FIRST && t + 1 < TT) {
      if (avail < t + 2) {                    // slow path: startup/hiccup
        int f;
        do { f = __hip_atomic_load(prog_in, __ATOMIC_RELAXED, __HIP_MEMORY_SCOPE_AGENT); } while (f < t + 2);
        avail = f;
      } else {
        f_new = __hip_atomic_load(prog_in, __ATOMIC_RELAXED, __HIP_MEMORY_SCOPE_AGENT);
      }
    }
    if (t + 1 < TT) {
      if constexpr (FIRST) {
        const float* p = xin + (size_t)(row0 + l15) * (TT * 32) + (size_t)(t + 1) * 32 + lg * 8;
        fn[0] = *reinterpret_cast<const f32x4*>(p);
        fn[1] = *reinterpret_cast<const f32x4*>(p + 4);
      } else {
#pragma unroll
        for (int kt = 0; kt < KTX; ++kt) {
          const ull* base = (ull*)ys +
              ((size_t)(t + 1) * (NB * 128) + (size_t)(row0 + l15) * 128 + kt * 32 + lg * 8) / 4;
          nx[2 * kt]     = __hip_atomic_load(base,     __ATOMIC_RELAXED, __HIP_MEMORY_SCOPE_AGENT);
          nx[2 * kt + 1] = __hip_atomic_load(base + 1, __ATOMIC_RELAXED, __HIP_MEMORY_SCOPE_AGENT);
        }
      }
    }

    // ---- gx burst: acc = bias + x(t)@Wih^T (fragments from registers) ----
    f32x4 acc[4];
#pragma unroll
    for (int j = 0; j < 4; ++j) acc[j] = bj[j];
#pragma unroll
    for (int kt = 0; kt < KTX; ++kt) {
      s16x8 xf;
      if constexpr (FIRST) {
#pragma unroll
        for (int e = 0; e < 4; ++e) {
          xf[e]     = (short)f2bf(fc[0][e]);
          xf[4 + e] = (short)f2bf(fc[1][e]);
        }
      } else {
        xf = __builtin_bit_cast(s16x8, U128{cu[2 * kt], cu[2 * kt + 1]});
      }
#pragma unroll
      for (int j = 0; j < 4; ++j) acc[j] = MFMA16(bfx[j][kt], xf, acc[j]);
    }

    // ---- chain: K=128 recurrent MFMA on h(t) (LDS: 4 b128/wave) ----
    const unsigned short* hbuf = h_s + (t & 1) * (16 * 128);
    unsigned short* nbuf = h_s + ((t + 1) & 1) * (16 * 128);
    s16x8 afr[4];
#pragma unroll
    for (int kt = 0; kt < 4; ++kt)
      afr[kt] = *reinterpret_cast<const s16x8*>(
          &hbuf[l15 * 128 + ((kt * 32 + lg * 8) ^ swzh)]);
#pragma unroll
    for (int kt = 0; kt < 4; ++kt)
#pragma unroll
      for (int j = 0; j < 4; ++j) acc[j] = MFMA16(bfh[j][kt], afr[kt], acc[j]);

    // ---- gates ----
    float hv[4];
#pragma unroll
    for (int r = 0; r < 4; ++r)
      hv[r] = lstm_cell(acc[0][r], acc[1][r], acc[2][r], acc[3][r], cst[r]);
    unsigned int plo, phi;
    asm("v_cvt_pk_bf16_f32 %0, %1, %2" : "=v"(plo) : "v"(hv[0]), "v"(hv[1]));
    asm("v_cvt_pk_bf16_f32 %0, %1, %2" : "=v"(phi) : "v"(hv[2]), "v"(hv[3]));
    const ull hpack = (ull)plo | ((ull)phi << 32);

    *reinterpret_cast<ull*>(&nbuf[l15 * 128 + (hcol ^ swzh)]) = hpack;

    if (!LAST) {
      __hip_atomic_store(
          (ull*)ys + ((size_t)t * (NB * 128) + (size_t)(row0 + l15) * 128 + hcol) / 4,
          hpack, __ATOMIC_RELAXED, __HIP_MEMORY_SCOPE_AGENT);
    } else if (t == TT - 1) {
      f32x4 o = {hv[0], hv[1], hv[2], hv[3]};
      *reinterpret_cast<f32x4*>(&hT[(row0 + l15) * 128 + hcol]) = o;  // f32 for LN
    }

    if (!FIRST && f_new > avail) avail = f_new;

    __syncthreads();  // h(t+1) visible; this step's ys store drained (vmcnt(0))
  };

  for (int t0 = 0; t0 < TT; t0 += 2) {        // 2-step unroll: frag ping-pong
    step(t0,     frA, frB, fxA, fxB);
    step(t0 + 1, frB, frA, fxB, fxA);
  }

  // ---- epilogue: all stores drained by final step's sync -> publish all ----
  if (!LAST && tid == 0)
    __hip_atomic_store(prog_out, TT, __ATOMIC_RELAXED, __HIP_MEMORY_SCOPE_AGENT);
}

__global__ __launch_bounds__(512, 2) void lstm_fused(
    const float* __restrict__ x, unsigned short* ys,
    const float* __restrict__ Wih0, const float* __restrict__ Whh0, const float* __restrict__ b0,
    const float* __restrict__ Wih1, const float* __restrict__ Whh1, const float* __restrict__ b1,
    const float* __restrict__ Wih2, const float* __restrict__ Whh2, const float* __restrict__ b2,
    float* __restrict__ hT, int* prog)
{
  __shared__ unsigned short h_s[2 * 16 * 128];
  const int lay = blockIdx.x >> 6;
  const int bblk = blockIdx.x & 63;
  if (lay == 0) {
    scan_layer<32, true, false>(h_s, x, ys, Wih0, Whh0, b0, nullptr,
                                nullptr, &prog[(0 * 64 + bblk) * 16], bblk);
  } else if (lay == 1) {
    scan_layer<128, false, false>(h_s, nullptr, ys, Wih1, Whh1, b1, nullptr,
                                  &prog[(0 * 64 + bblk) * 16], &prog[(1 * 64 + bblk) * 16], bblk);
  } else {
    scan_layer<128, false, true>(h_s, nullptr, ys, Wih2, Whh2, b2, hT,
                                 &prog[(1 * 64 + bblk) * 16], nullptr, bblk);
  }
}

__global__ void init_flags(int* prog) {
  prog[threadIdx.x] = 0;
  prog[threadIdx.x + 1024] = 0;
}

// ---------------------------------------------------------------------------
// Head: LN + fc1 + fc2 + 4 heads + reparam + dec1 + dec2 + out. 4 rows/block.
// ---------------------------------------------------------------------------
__global__ __launch_bounds__(256) void head_kernel(
    const float* __restrict__ hT, const float* __restrict__ eps,
    const float* __restrict__ u, const float* __restrict__ choice,
    const float* __restrict__ ln_g, const float* __restrict__ ln_b,
    const float* __restrict__ fc1_W, const float* __restrict__ fc1_b,
    const float* __restrict__ fc2_W, const float* __restrict__ fc2_b,
    const float* __restrict__ mean_W, const float* __restrict__ mean_b,
    const float* __restrict__ logvar_W, const float* __restrict__ logvar_b,
    const float* __restrict__ scale_W, const float* __restrict__ scale_b,
    const float* __restrict__ shape_W, const float* __restrict__ shape_b,
    const float* __restrict__ dec1_W, const float* __restrict__ dec1_b,
    const float* __restrict__ dec2_W, const float* __restrict__ dec2_b,
    const float* __restrict__ out_W, const float* __restrict__ out_b,
    const float* __restrict__ pi_params, float* __restrict__ out)
{
  __shared__ float s_hn[4][128];
  __shared__ float s_a[4][128];
  __shared__ float s_b2[4][64];
  __shared__ float s_z[4][64];
  __shared__ float s_d1[4][128];
  __shared__ float s_d2[4][512];

  const int tid = threadIdx.x;
  const int gr0 = blockIdx.x * 4;

  { // LayerNorm: one wave per row
    const int wvr = tid >> 6, lnn = tid & 63;
    const float v0 = hT[(gr0 + wvr) * 128 + lnn];
    const float v1 = hT[(gr0 + wvr) * 128 + 64 + lnn];
    float s = v0 + v1, s2 = v0 * v0 + v1 * v1;
#pragma unroll
    for (int off = 32; off; off >>= 1) {
      s  += __shfl_xor(s, off, 64);
      s2 += __shfl_xor(s2, off, 64);
    }
    const float mu  = s * (1.f / 128.f);
    const float var = s2 * (1.f / 128.f) - mu * mu;
    const float rs  = rsqrtf(var + 1e-5f);
    s_hn[wvr][lnn]      = (v0 - mu) * rs * ln_g[lnn]      + ln_b[lnn];
    s_hn[wvr][lnn + 64] = (v1 - mu) * rs * ln_g[lnn + 64] + ln_b[lnn + 64];
  }
  __syncthreads();
#pragma unroll
  for (int p = 0; p < 2; ++p) { // fc1 (128x128) + relu
    const int idx = tid + p * 256, row = idx >> 7, col = idx & 127;
    const float* w = fc1_W + col * 128;
    float a = fc1_b[col];
    for (int k = 0; k < 128; k += 4)
      a += s_hn[row][k] * w[k] + s_hn[row][k + 1] * w[k + 1] +
           s_hn[row][k + 2] * w[k + 2] + s_hn[row][k + 3] * w[k + 3];
    s_a[row][col] = fmaxf(a, 0.f);
  }
  __syncthreads();
  { // fc2 (64x128) + relu
    const int row = tid >> 6, col = tid & 63;
    const float* w = fc2_W + col * 128;
    float a = fc2_b[col];
    for (int k = 0; k < 128; ++k) a += s_a[row][k] * w[k];
    s_b2[row][col] = fmaxf(a, 0.f);
  }
  __syncthreads();
  { // 4 heads + reparameterize
    const int row = tid >> 6, c = tid & 63;
    const int gr = gr0 + row;
    float am = mean_b[c], al = logvar_b[c], as_ = scale_b[c], ah = shape_b[c];
    for (int k = 0; k < 64; ++k) {
      const float hv = s_b2[row][k];
      am  += hv * mean_W[c * 64 + k];
      al  += hv * logvar_W[c * 64 + k];
      as_ += hv * scale_W[c * 64 + k];
      ah  += hv * shape_W[c * 64 + k];
    }
    const float zsc = fexp2(as_ * LOG2E);
    const float zsh = fmaxf(ah, 1e-6f);
    out[131072 + gr * 64 + c] = am;
    out[196608 + gr * 64 + c] = al;
    out[262144 + gr * 64 + c] = zsc;
    out[327680 + gr * 64 + c] = zsh;
    const float ev = eps[gr * 64 + c], uv = u[gr * 64 + c], cv = choice[gr];
    const float zg = am + ev * fexp2(0.72134752044448170f * al);  // exp(0.5*logvar)
    const float p0 = pi_params[0], p1 = pi_params[1];
    const float pi0 = 1.f / (1.f + expf(p1 - p0));
    const float tq = -zsh * logf(1.f - uv);                       // expm1: no cancel
    const float zp = zsc * frcp(zsh) * expm1f(tq);
    s_z[row][c] = (cv < pi0) ? zg : zp;
  }
  __syncthreads();
#pragma unroll
  for (int p = 0; p < 2; ++p) { // dec1 (128x64) + relu
    const int idx = tid + p * 256, row = idx >> 7, col = idx & 127;
    const float* w = dec1_W + col * 64;
    float a = dec1_b[col];
    for (int k = 0; k < 64; ++k) a += s_z[row][k] * w[k];
    s_d1[row][col] = fmaxf(a, 0.f);
  }
  __syncthreads();
  for (int o = tid; o < 2000; o += 256) { // dec2 (500x128) + relu
    const int row = o / 500, col = o % 500;
    const float* w = dec2_W + col * 128;
    float a = dec2_b[col];
    for (int k = 0; k < 128; ++k) a += s_d1[row][k] * w[k];
    s_d2[row][col] = fmaxf(a, 0.f);
  }
  __syncthreads();
#pragma unroll
  for (int p = 0; p < 2; ++p) { // out (128x500)
    const int idx = tid + p * 256, row = idx >> 7, col = idx & 127;
    const float* w = out_W + col * 500;
    float a = out_b[col];
    for (int k = 0; k < 500; ++k) a += s_d2[row][k] * w[k];
    out[(gr0 + row) * 128 + col] = a;
  }
}

// ---------------------------------------------------------------------------
extern "C" void kernel_launch(void* const* d_in, const int* in_sizes, int n_in,
                              void* d_out, int out_size, void* d_ws, size_t ws_size,
                              hipStream_t stream) {
  const float* x      = (const float*)d_in[0];
  const float* eps    = (const float*)d_in[1];
  const float* u      = (const float*)d_in[2];
  const float* choice = (const float*)d_in[3];
  const float* Wih0 = (const float*)d_in[4],  *Whh0 = (const float*)d_in[5],  *b0 = (const float*)d_in[6];
  const float* Wih1 = (const float*)d_in[7],  *Whh1 = (const float*)d_in[8],  *b1 = (const float*)d_in[9];
  const float* Wih2 = (const float*)d_in[10], *Whh2 = (const float*)d_in[11], *b2 = (const float*)d_in[12];
  const float* ln_g = (const float*)d_in[13], *ln_b = (const float*)d_in[14];
  const float* fc1_W = (const float*)d_in[15], *fc1_b = (const float*)d_in[16];
  const float* fc2_W = (const float*)d_in[17], *fc2_b = (const float*)d_in[18];
  const float* mean_W = (const float*)d_in[19], *mean_b = (const float*)d_in[20];
  const float* logvar_W = (const float*)d_in[21], *logvar_b = (const float*)d_in[22];
  const float* scale_W = (const float*)d_in[23], *scale_b = (const float*)d_in[24];
  const float* shape_W = (const float*)d_in[25], *shape_b = (const float*)d_in[26];
  const float* dec1_W = (const float*)d_in[27], *dec1_b = (const float*)d_in[28];
  const float* dec2_W = (const float*)d_in[29], *dec2_b = (const float*)d_in[30];
  const float* out_W = (const float*)d_in[31], *out_b = (const float*)d_in[32];
  const float* pi_params = (const float*)d_in[33];

  unsigned short* ys = (unsigned short*)d_ws;                        // 128 MiB
  float* hT  = (float*)((char*)d_ws + (size_t)512 * 1024 * 128 * 2); // 512 KiB
  int*   prog = (int*)((char*)d_ws + (size_t)512 * 1024 * 128 * 2 + (size_t)1024 * 128 * 4);

  init_flags<<<1, 1024, 0, stream>>>(prog);
  lstm_fused<<<192, 512, 0, stream>>>(x, ys, Wih0, Whh0, b0, Wih1, Whh1, b1,
                                      Wih2, Whh2, b2, hT, prog);
  head_kernel<<<256, 256, 0, stream>>>(hT, eps, u, choice, ln_g, ln_b,
      fc1_W, fc1_b, fc2_W, fc2_b, mean_W, mean_b, logvar_W, logvar_b,
      scale_W, scale_b, shape_W, shape_b, dec1_W, dec1_b, dec2_W, dec2_b,
      out_W, out_b, pi_params, (float*)d_out);
}